// Round 6
// baseline (225.254 us; speedup 1.0000x reference)
//
#include <hip/hip_runtime.h>
#include <hip/hip_bf16.h>
#include <math.h>

// ---- problem constants ----
#define TOKS   65536      // B*D*H*W
#define DIMC   192
#define NTOK   128
#define MLPH   384
#define QSCALE 0.17677669529663687f

typedef unsigned short u16;
typedef unsigned int   u32;
typedef __attribute__((ext_vector_type(8))) short bf16x8;
typedef __attribute__((ext_vector_type(4))) float f32x4;

static __device__ __forceinline__ float gelu_exact(float v) {
    return 0.5f * v * (1.f + erff(v * 0.70710678118654752f));
}
static __device__ __forceinline__ u16 f2bf(float f) {
    __hip_bfloat16 h = __float2bfloat16(f);
    return *reinterpret_cast<u16*>(&h);
}
static __device__ __forceinline__ float bf2f(u16 b) {
    u32 u = ((u32)b) << 16;
    float f;
    __builtin_memcpy(&f, &u, 4);
    return f;
}
static __device__ __forceinline__ void gl_lds16(const u16* g, u16* l) {
    __builtin_amdgcn_global_load_lds(
        (const __attribute__((address_space(1))) void*)g,
        (__attribute__((address_space(3))) void*)l, 16, 0, 0);
}

// workspace layout (float offsets). bf16 buffers occupy elems/2 floats.
#define OFF_XW   0u          // attn_out bf16 [65536][192]
#define OFF_Q    6291456u    // q bf16 [wh][t][32]; h bf16 [65536][384] overlays Q..V
#define OFF_K    12582912u   // k bf16
#define OFF_V    18874368u   // vT bf16 [wh][d][128]
#define OFF_BF   25165824u   // biasw bf16 [6][128][128] (fragment-tiled)
#define OFF_WB   25264128u   // bf16 weights: qkv | proj @110592 | fc1 @147456 | fc2 @221184

// ---------------- weight fp32 -> bf16 ----------------
__global__ __launch_bounds__(256) void k_cvt(const float* __restrict__ a,
                                             const float* __restrict__ b,
                                             const float* __restrict__ c,
                                             const float* __restrict__ d,
                                             u16* __restrict__ o) {
    int i = blockIdx.x * 256 + threadIdx.x;   // 1152*256 = 294912 exact
    float v;
    if (i < 110592) v = a[i];
    else if (i < 147456) v = b[i - 110592];
    else if (i < 221184) v = c[i - 147456];
    else v = d[i - 221184];
    o[i] = f2bf(v);
}

// ---------------- rel-pos bias gather -> bf16, MFMA-fragment-tiled ----------------
__global__ __launch_bounds__(256) void k_bias(const float* __restrict__ rpb,
                                              const int* __restrict__ rpi,
                                              u16* __restrict__ biasw) {
    int idx = blockIdx.x * 256 + threadIdx.x;   // 6*128*128 = 98304 exact
    int h = idx >> 14;
    int n = (idx >> 7) & 127;
    int slot = idx & 127;
    int m = ((slot & 7) << 4) + (slot >> 3);
    biasw[idx] = f2bf(rpb[rpi[n * 128 + m] * 6 + h]);
}

// ---------------- fused (LN +) GEMM, A staged once, n-tile loop ----------------
// A tile: 128 rows x KD cols bf16, stored as 3 k-tiles [128][64] with slot-XOR
// swizzle: original 16B-slot s of row r lives at position s ^ (r&7).
// MODE 0: LN1(roll-permute gather from x fp32) -> QKV epilogue (q/k scaled bf16, vT bf16)
// MODE 1: A = attn_out bf16 -> proj -> roll-reverse scatter += aux(x) -> xres fp32
// MODE 2: LN2(from xres fp32) -> fc1 -> gelu -> h bf16
// MODE 3: A = h bf16 (K=384, two stage passes) -> fc2 -> += aux(xres) -> xres fp32
template<int MODE>
__global__ __launch_bounds__(256) void k_fgemm(
    const void* __restrict__ srcA, const u16* __restrict__ W,
    const float* __restrict__ bias, void* __restrict__ outp,
    const float* __restrict__ aux,
    u16* __restrict__ q_o, u16* __restrict__ k_o, u16* __restrict__ v_o,
    const float* __restrict__ gam, const float* __restrict__ bet)
{
    constexpr int KD = (MODE == 3) ? 384 : 192;
    constexpr int NT = (MODE == 0) ? 9 : (MODE == 2 ? 6 : 3);
    __shared__ u16 As[3 * 128 * 64];          // 48 KB
    const int tid = threadIdx.x;
    const int wv = tid >> 6, l = tid & 63;
    const int l15 = l & 15, g4 = l >> 4;
    const int wm = wv >> 1, wn = wv & 1;
    const size_t m0 = (size_t)blockIdx.x * 128;

    auto STAGEP = [&](int p) {                 // stage 48 KB: k-cols [p*192, p*192+192)
        const u16* Ab = (const u16*)srcA + m0 * KD + p * 192;
        #pragma unroll
        for (int j = 0; j < 12; ++j) {
            int cid = j * 256 + wv * 64 + l;   // 16B chunk id 0..3071
            int tile = cid >> 10, r = (cid >> 3) & 127, sl = cid & 7;
            int sc = sl ^ (r & 7);             // pre-swizzled global source slot
            gl_lds16(Ab + (size_t)r * KD + tile * 64 + sc * 8,
                     &As[(size_t)(j * 256 + wv * 64) * 8]);
        }
    };

    if (MODE == 0 || MODE == 2) {
        const float* xs = (const float*)srcA;
        float g0 = gam[l], g1 = gam[64 + l], g2 = gam[128 + l];
        float b0 = bet[l], b1 = bet[64 + l], b2 = bet[128 + l];
        for (int it = 0; it < 32; ++it) {
            int t = it * 4 + wv;               // local token 0..127
            size_t srcrow;
            if (MODE == 0) {
                int w_all = (int)blockIdx.x;
                int b = w_all >> 8, rem = w_all & 255;
                int di = rem >> 6, hi = (rem >> 3) & 7, wi = rem & 7;
                int qd = (di * 2 + (t >> 6) + 1) & 7;
                int qh = (hi * 8 + ((t >> 3) & 7) + 4) & 63;
                int qw = (wi * 8 + (t & 7) + 4) & 63;
                srcrow = ((size_t)(((b * 8 + qd) * 64 + qh) * 64 + qw)) * DIMC;
            } else {
                srcrow = (m0 + t) * DIMC;
            }
            float v0 = xs[srcrow + l], v1 = xs[srcrow + 64 + l], v2 = xs[srcrow + 128 + l];
            float s = v0 + v1 + v2, sq = v0 * v0 + v1 * v1 + v2 * v2;
            #pragma unroll
            for (int off = 32; off; off >>= 1) { s += __shfl_xor(s, off); sq += __shfl_xor(sq, off); }
            float mu = s * (1.f / 192.f);
            float rstd = rsqrtf(sq * (1.f / 192.f) - mu * mu + 1e-5f);
            int se = (((l >> 3) ^ (t & 7)) << 3) + (l & 7);   // swizzled elem within tile
            As[(0 * 128 + t) * 64 + se] = f2bf((v0 - mu) * rstd * g0 + b0);
            As[(1 * 128 + t) * 64 + se] = f2bf((v1 - mu) * rstd * g1 + b1);
            As[(2 * 128 + t) * 64 + se] = f2bf((v2 - mu) * rstd * g2 + b2);
        }
    } else {
        STAGEP(0);
    }
    __syncthreads();

    // one k-subtile accumulate: kglob = global k/32 index (W cols), ktloc = LDS tile-local
    auto KSTEP = [&](f32x4 (&acc)[4][2], int n0, int kglob, int ktloc) {
        bf16x8 bfr[2];
        #pragma unroll
        for (int nt = 0; nt < 2; ++nt)
            bfr[nt] = *(const bf16x8*)&W[(size_t)(n0 + wn * 32 + nt * 16 + l15) * KD
                                         + kglob * 32 + g4 * 8];
        #pragma unroll
        for (int mt = 0; mt < 4; ++mt) {
            int row  = wm * 64 + mt * 16 + l15;
            int slot = ((ktloc & 1) * 4 + g4) ^ (row & 7);
            bf16x8 afr = *(const bf16x8*)&As[(size_t)((ktloc >> 1) * 128 + row) * 64 + slot * 8];
            #pragma unroll
            for (int nt = 0; nt < 2; ++nt)
                acc[mt][nt] = __builtin_amdgcn_mfma_f32_16x16x32_bf16(afr, bfr[nt],
                                                                      acc[mt][nt], 0, 0, 0);
        }
    };

    auto EPI = [&](int n0, f32x4 (&acc)[4][2]) {
        #pragma unroll
        for (int mt = 0; mt < 4; ++mt) {
            #pragma unroll
            for (int nt = 0; nt < 2; ++nt) {
                int n  = n0 + wn * 32 + nt * 16 + l15;
                float bb = bias[n];
                int t0 = wm * 64 + mt * 16 + g4 * 4;
                if (MODE == 0) {
                    int sel = (n >= 384) ? 2 : (n >= 192 ? 1 : 0);
                    int rem = n - sel * 192;
                    int head = rem >> 5, dd = rem & 31;
                    int w = (int)blockIdx.x;
                    size_t b9 = (size_t)(w * 6 + head) * 4096;
                    if (sel < 2) {
                        u16* dst = sel ? k_o : q_o;
                        float scl = sel ? 1.f : QSCALE;
                        #pragma unroll
                        for (int reg = 0; reg < 4; ++reg)
                            dst[b9 + (size_t)(t0 + reg) * 32 + dd] = f2bf((acc[mt][nt][reg] + bb) * scl);
                    } else {
                        ushort4 uv;
                        uv.x = f2bf(acc[mt][nt][0] + bb); uv.y = f2bf(acc[mt][nt][1] + bb);
                        uv.z = f2bf(acc[mt][nt][2] + bb); uv.w = f2bf(acc[mt][nt][3] + bb);
                        *(ushort4*)&v_o[b9 + (size_t)dd * 128 + t0] = uv;
                    }
                } else if (MODE == 1) {
                    float* out = (float*)outp;
                    #pragma unroll
                    for (int reg = 0; reg < 4; ++reg) {
                        int m = (int)m0 + t0 + reg;
                        int w_all = m >> 7, tt = m & 127;
                        int b  = w_all >> 8, rem = w_all & 255;
                        int di = rem >> 6, hi = (rem >> 3) & 7, wi = rem & 7;
                        int qd = (di * 2 + (tt >> 6) + 1) & 7;
                        int qh = (hi * 8 + ((tt >> 3) & 7) + 4) & 63;
                        int qw = (wi * 8 + (tt & 7) + 4) & 63;
                        size_t dtok = (size_t)(((b * 8 + qd) * 64 + qh) * 64 + qw);
                        out[dtok * DIMC + n] = acc[mt][nt][reg] + bb + aux[dtok * DIMC + n];
                    }
                } else if (MODE == 2) {
                    u16* out = (u16*)outp;
                    #pragma unroll
                    for (int reg = 0; reg < 4; ++reg) {
                        size_t m = m0 + t0 + reg;
                        out[m * MLPH + n] = f2bf(gelu_exact(acc[mt][nt][reg] + bb));
                    }
                } else {
                    float* out = (float*)outp;
                    #pragma unroll
                    for (int reg = 0; reg < 4; ++reg) {
                        size_t m = m0 + t0 + reg;
                        out[m * DIMC + n] = acc[mt][nt][reg] + bb + aux[m * DIMC + n];
                    }
                }
            }
        }
    };

    if (MODE != 3) {
        #pragma unroll 1
        for (int n0i = 0; n0i < NT; ++n0i) {
            f32x4 acc[4][2] = {};
            #pragma unroll
            for (int kt = 0; kt < 6; ++kt) KSTEP(acc, n0i * 64, kt, kt);
            EPI(n0i * 64, acc);
        }
    } else {
        f32x4 a0[4][2] = {}, a1[4][2] = {}, a2[4][2] = {};
        #pragma unroll 1
        for (int kt = 0; kt < 6; ++kt) {
            KSTEP(a0, 0,   kt, kt);
            KSTEP(a1, 64,  kt, kt);
            KSTEP(a2, 128, kt, kt);
        }
        __syncthreads();
        STAGEP(1);
        __syncthreads();
        #pragma unroll 1
        for (int kt = 0; kt < 6; ++kt) {
            KSTEP(a0, 0,   6 + kt, kt);
            KSTEP(a1, 64,  6 + kt, kt);
            KSTEP(a2, 128, 6 + kt, kt);
        }
        EPI(0, a0); EPI(64, a1); EPI(128, a2);
    }
}

// ---------------- MFMA attention (unchanged from round 5) ----------------
__global__ __launch_bounds__(256) void k_attn(const u16* __restrict__ qb,
                                              const u16* __restrict__ kb,
                                              const u16* __restrict__ vb,
                                              const u16* __restrict__ biasw,
                                              u16* __restrict__ attn_out) {
    __shared__ u16 Pl[4][32 * 128];     // 32 KB
    int wh = blockIdx.x;
    int w_all = wh / 6, head = wh - w_all * 6;
    int wl = w_all & 255;
    int tid = threadIdx.x;
    int wv = tid >> 6, l = tid & 63;
    int l15 = l & 15, g4 = l >> 4;
    size_t base = (size_t)wh * 4096;
    const u16* qg = qb + base;
    const u16* kg = kb + base;
    const u16* vg = vb + base;           // [d][m]
    int rowb = wv * 32;

    bf16x8 qa[2];
    #pragma unroll
    for (int rt = 0; rt < 2; ++rt)
        qa[rt] = *(const bf16x8*)&qg[(size_t)(rowb + rt * 16 + l15) * 32 + g4 * 8];

    f32x4 s[2][8] = {};
    #pragma unroll
    for (int ct = 0; ct < 8; ++ct) {
        bf16x8 kf = *(const bf16x8*)&kg[(size_t)(ct * 16 + l15) * 32 + g4 * 8];
        s[0][ct] = __builtin_amdgcn_mfma_f32_16x16x32_bf16(qa[0], kf, s[0][ct], 0, 0, 0);
        s[1][ct] = __builtin_amdgcn_mfma_f32_16x16x32_bf16(qa[1], kf, s[1][ct], 0, 0, 0);
    }

    int di = wl >> 6, hi = (wl >> 3) & 7, wi = wl & 7;
    auto rcode = [&](int t) {
        int d = di * 2 + (t >> 6);
        int h = hi * 8 + ((t >> 3) & 7);
        int w = wi * 8 + (t & 7);
        int rd = (d < 6) ? 0 : (d < 7 ? 1 : 2);
        int rh = (h < 56) ? 0 : (h < 60 ? 1 : 2);
        int rw = (w < 56) ? 0 : (w < 60 ? 1 : 2);
        return rd * 9 + rh * 3 + rw;
    };
    int rm[8];
    #pragma unroll
    for (int ct = 0; ct < 8; ++ct) rm[ct] = rcode(ct * 16 + l15);

    const u16* bh = biasw + (size_t)head * 16384;
    #pragma unroll
    for (int rt = 0; rt < 2; ++rt)
        #pragma unroll
        for (int reg = 0; reg < 4; ++reg) {
            int n = rowb + rt * 16 + g4 * 4 + reg;
            int rn = rcode(n);
            bf16x8 bv = *(const bf16x8*)&bh[(size_t)n * 128 + l15 * 8];
            #pragma unroll
            for (int ct = 0; ct < 8; ++ct) {
                float mval = (rn == rm[ct]) ? 0.f : -100.f;
                s[rt][ct][reg] += bf2f((u16)bv[ct]) + mval;
            }
        }

    u16* Pw = Pl[wv];
    #pragma unroll
    for (int rt = 0; rt < 2; ++rt)
        #pragma unroll
        for (int reg = 0; reg < 4; ++reg) {
            float mx = -1e30f;
            #pragma unroll
            for (int ct = 0; ct < 8; ++ct) mx = fmaxf(mx, s[rt][ct][reg]);
            #pragma unroll
            for (int off = 1; off < 16; off <<= 1) mx = fmaxf(mx, __shfl_xor(mx, off));
            float sum = 0.f;
            #pragma unroll
            for (int ct = 0; ct < 8; ++ct) {
                float p = __expf(s[rt][ct][reg] - mx);
                s[rt][ct][reg] = p; sum += p;
            }
            #pragma unroll
            for (int off = 1; off < 16; off <<= 1) sum += __shfl_xor(sum, off);
            float inv = 1.f / sum;
            int nloc = rt * 16 + g4 * 4 + reg;
            int sw = ((nloc >> 2) & 3) << 4;
            #pragma unroll
            for (int ct = 0; ct < 8; ++ct) {
                int m = ct * 16 + l15;
                Pw[nloc * 128 + (m ^ sw)] = f2bf(s[rt][ct][reg] * inv);
            }
        }
    __syncthreads();

    f32x4 o[2][2] = {};
    #pragma unroll
    for (int kt = 0; kt < 4; ++kt) {
        bf16x8 vf[2];
        #pragma unroll
        for (int dt = 0; dt < 2; ++dt)
            vf[dt] = *(const bf16x8*)&vg[(size_t)(dt * 16 + l15) * 128 + kt * 32 + g4 * 8];
        #pragma unroll
        for (int rt = 0; rt < 2; ++rt) {
            int nloc = rt * 16 + l15;
            int sw = ((nloc >> 2) & 3) << 4;
            int m8 = kt * 32 + g4 * 8;
            bf16x8 pa = *(const bf16x8*)&Pw[nloc * 128 + (m8 ^ sw)];
            #pragma unroll
            for (int dt = 0; dt < 2; ++dt)
                o[rt][dt] = __builtin_amdgcn_mfma_f32_16x16x32_bf16(pa, vf[dt], o[rt][dt], 0, 0, 0);
        }
    }

    #pragma unroll
    for (int rt = 0; rt < 2; ++rt)
        #pragma unroll
        for (int dt = 0; dt < 2; ++dt)
            #pragma unroll
            for (int reg = 0; reg < 4; ++reg) {
                int n = rowb + rt * 16 + g4 * 4 + reg;
                int d = dt * 16 + l15;
                attn_out[((size_t)(w_all * 128 + n)) * DIMC + head * 32 + d] = f2bf(o[rt][dt][reg]);
            }
}

// ---------------- launch ----------------
extern "C" void kernel_launch(void* const* d_in, const int* in_sizes, int n_in,
                              void* d_out, int out_size, void* d_ws, size_t ws_size,
                              hipStream_t stream) {
    const float* x      = (const float*)d_in[0];
    const int*   rpi    = (const int*)d_in[2];
    const float* gamma1 = (const float*)d_in[3];
    const float* beta1  = (const float*)d_in[4];
    const float* w_qkv  = (const float*)d_in[5];
    const float* b_qkv  = (const float*)d_in[6];
    const float* rpb    = (const float*)d_in[7];
    const float* w_proj = (const float*)d_in[8];
    const float* b_proj = (const float*)d_in[9];
    const float* gamma2 = (const float*)d_in[10];
    const float* beta2  = (const float*)d_in[11];
    const float* w_fc1  = (const float*)d_in[12];
    const float* b_fc1  = (const float*)d_in[13];
    const float* w_fc2  = (const float*)d_in[14];
    const float* b_fc2  = (const float*)d_in[15];

    float* ws    = (float*)d_ws;
    u16*   xwu   = (u16*)(ws + OFF_XW);   // attn_out bf16
    u16*   qbu   = (u16*)(ws + OFF_Q);
    u16*   kbu   = (u16*)(ws + OFF_K);
    u16*   vbu   = (u16*)(ws + OFF_V);
    u16*   hbu   = (u16*)(ws + OFF_Q);    // fc1 out overlays q..v (dead after attn)
    u16*   biasw = (u16*)(ws + OFF_BF);
    u16*   wb    = (u16*)(ws + OFF_WB);
    float* xres  = (float*)d_out;

    const u16* wqkv_b  = wb;
    const u16* wproj_b = wb + 110592;
    const u16* wfc1_b  = wb + 147456;
    const u16* wfc2_b  = wb + 221184;

    k_cvt<<<1152, 256, 0, stream>>>(w_qkv, w_proj, w_fc1, w_fc2, wb);
    k_bias<<<384, 256, 0, stream>>>(rpb, rpi, biasw);
    k_fgemm<0><<<512, 256, 0, stream>>>(x, wqkv_b, b_qkv, nullptr, nullptr,
                                        qbu, kbu, vbu, gamma1, beta1);
    k_attn<<<3072, 256, 0, stream>>>(qbu, kbu, vbu, biasw, xwu);
    k_fgemm<1><<<512, 256, 0, stream>>>(xwu, wproj_b, b_proj, xres, x,
                                        nullptr, nullptr, nullptr, nullptr, nullptr);
    k_fgemm<2><<<512, 256, 0, stream>>>(xres, wfc1_b, b_fc1, hbu, nullptr,
                                        nullptr, nullptr, nullptr, gamma2, beta2);
    k_fgemm<3><<<512, 256, 0, stream>>>(hbu, wfc2_b, b_fc2, xres, xres,
                                        nullptr, nullptr, nullptr, nullptr, nullptr);
}